// Round 1
// baseline (242.074 us; speedup 1.0000x reference)
//
#include <hip/hip_runtime.h>

// db4 DWT, mode='symmetric', matching the JAX reference exactly:
//   ext[i] = x[reflect(i-6)],  reflect: g<0 -> -1-g ; g>=N -> 2N-1-g
//   cA[k] = sum_t ext[2k+t] * w[t]
//   cD[k] = sum_t ext[2k+t] * ((t&1) ? -w[7-t] : +w[7-t])
//   K = (N+7)/2 ; outputs: cA (B,K) || cD (B,K) || x3 (B,8) passthrough

#define TILE_K 2048
#define EXT_FLOATS 4104   // covers x[2*k_start-8 .. 2*k_start+4095]
#define EXT_F4 1026

__global__ __launch_bounds__(256) void dwt_db4_kernel(
    const float* __restrict__ x, const float* __restrict__ w,
    float* __restrict__ out, int B, int N, int K, int tiles_per_row)
{
    __shared__ float lds[EXT_FLOATS];
    const int blk  = blockIdx.x;
    const int row  = blk / tiles_per_row;
    const int tile = blk - row * tiles_per_row;
    const int k_start = tile * TILE_K;
    const long long gbase = 2LL * k_start - 8;   // x-index of lds[0]; 16B-aligned
    const float* __restrict__ xr = x + (long long)row * N;
    const int tid = threadIdx.x;

    // ---- stage input window into LDS ----
    if (gbase >= 0 && gbase + EXT_FLOATS <= (long long)N) {
        // interior tile: pure float4 coalesced copy (15 of 17 tiles)
        const float4* __restrict__ src = reinterpret_cast<const float4*>(xr + gbase);
        float4* dst = reinterpret_cast<float4*>(lds);
        #pragma unroll
        for (int v = 0; v < 5; ++v) {
            int idx = tid + v * 256;
            if (idx < EXT_F4) dst[idx] = src[idx];
        }
    } else {
        // edge tile: scalar loads with symmetric reflection
        for (int idx = tid; idx < EXT_FLOATS; idx += 256) {
            long long g = gbase + idx;
            if (g < 0) g = -1 - g;
            if (g >= (long long)N) g = 2LL * N - 1 - g;
            lds[idx] = xr[g];
        }
    }

    // filter taps (global reads are broadcast + L2-cached; negligible)
    float wl[8], wh[8];
    #pragma unroll
    for (int t = 0; t < 8; ++t) wl[t] = w[t];
    #pragma unroll
    for (int t = 0; t < 8; ++t) wh[t] = (t & 1) ? -wl[7 - t] : wl[7 - t];

    __syncthreads();

    float* __restrict__ outA = out;
    float* __restrict__ outD = out + (long long)B * K;
    const float2* __restrict__ lds2 = reinterpret_cast<const float2*>(lds);

    // each thread: 8 strided outputs; window floats [2*kl+2 .. 2*kl+9]
    // -> float2 indices kl+1 .. kl+4 (even byte addr; lanes contiguous -> no bank conflicts)
    #pragma unroll
    for (int i = 0; i < 8; ++i) {
        const int kl = tid + i * 256;
        const int kg = k_start + kl;
        if (kg < K) {
            float2 q0 = lds2[kl + 1];
            float2 q1 = lds2[kl + 2];
            float2 q2 = lds2[kl + 3];
            float2 q3 = lds2[kl + 4];
            float a, d;
            a = q0.x * wl[0];            d = q0.x * wh[0];
            a = fmaf(q0.y, wl[1], a);    d = fmaf(q0.y, wh[1], d);
            a = fmaf(q1.x, wl[2], a);    d = fmaf(q1.x, wh[2], d);
            a = fmaf(q1.y, wl[3], a);    d = fmaf(q1.y, wh[3], d);
            a = fmaf(q2.x, wl[4], a);    d = fmaf(q2.x, wh[4], d);
            a = fmaf(q2.y, wl[5], a);    d = fmaf(q2.y, wh[5], d);
            a = fmaf(q3.x, wl[6], a);    d = fmaf(q3.x, wh[6], d);
            a = fmaf(q3.y, wl[7], a);    d = fmaf(q3.y, wh[7], d);
            const long long o = (long long)row * K + kg;
            outA[o] = a;   // coalesced scalar stores (row base is odd-float offset,
            outD[o] = d;   // so 16B-vector stores would be misaligned UB)
        }
    }
}

__global__ void copy_tail_kernel(const float* __restrict__ src,
                                 float* __restrict__ dst, int n)
{
    int i = blockIdx.x * blockDim.x + threadIdx.x;
    if (i < n) dst[i] = src[i];
}

extern "C" void kernel_launch(void* const* d_in, const int* in_sizes, int n_in,
                              void* d_out, int out_size, void* d_ws, size_t ws_size,
                              hipStream_t stream) {
    const float* x1 = (const float*)d_in[0];
    // d_in[1] = x2: unused by the reference
    const float* x3 = (const float*)d_in[2];
    const float* w  = (const float*)d_in[3];
    float* out = (float*)d_out;

    const int B = in_sizes[2] / 8;        // 512
    const int N = in_sizes[0] / B;        // 65536
    const int K = (N + 7) / 2;            // 32771
    const int tiles = (K + TILE_K - 1) / TILE_K;   // 17

    dwt_db4_kernel<<<B * tiles, 256, 0, stream>>>(x1, w, out, B, N, K, tiles);

    const int n3 = in_sizes[2];           // 4096
    copy_tail_kernel<<<(n3 + 255) / 256, 256, 0, stream>>>(
        x3, out + 2LL * B * K, n3);
}